// Round 3
// baseline (70516.077 us; speedup 1.0000x reference)
//
#include <hip/hip_runtime.h>
#include <hip/hip_bf16.h>
#include <hip/hip_cooperative_groups.h>

namespace cg = cooperative_groups;

// QLSTM (S=512,B=256,D=256,H=256,E=512), f32 in/out, bf16 MFMA internals.
// Persistent cooperative kernel; 3 vendor grid barriers per step:
//   A  : q,k,vT = [x_t|hx] @ [Wq|Wk|Wv]^T             (all 256 WGs)
//   BCD: scores -> softmax -> attn, per 16-row strip   (16 WGs, LDS-local)
//   E  : 4 gate GEMMs + LSTM update                    (all 256 WGs)

typedef __hip_bfloat16 bf16;
typedef __attribute__((ext_vector_type(8))) short bf16x8;   // 8 bf16 = 4 VGPR
typedef __attribute__((ext_vector_type(4))) float f32x4;

#define SEQ 512
#define BB  256
#define DD  256
#define HH  256
#define EE  512
#define NWG 256
#define QK_SCALE 0.04419417382415922f  // 1/sqrt(512)

// ws layout (bytes)
#define WS_Q    0          // bf16 [256][512]
#define WS_K    262144     // bf16 [256][512]
#define WS_VT   524288     // bf16 [512][256]  (v transposed)
#define WS_AT   786432     // bf16 [256][512]  (attn)
#define WS_HX   1048576    // bf16 [256][256]
#define WS_CX   1179648    // f32  [256][256]
#define WS_WQ   1441792    // bf16 [512][512]
#define WS_WK   1966080    // bf16 [512][512]
#define WS_WV   2490368    // bf16 [512][512]
#define WS_WF   3014656    // bf16 [256][512]
#define WS_WI   3276800    // bf16 [256][512]
#define WS_WG   3538944    // bf16 [256][512]
#define WS_WO   3801088    // bf16 [256][512]
#define WS_END  4063232

__device__ __forceinline__ float sigm(float x) { return 1.0f / (1.0f + __expf(-x)); }

__device__ __forceinline__ short f2bf_s(float f) {
  bf16 h = __float2bfloat16(f);
  return *reinterpret_cast<short*>(&h);
}

__device__ __forceinline__ bf16x8 cvt8(float4 a, float4 b) {
  bf16x8 r;
  r[0] = f2bf_s(a.x); r[1] = f2bf_s(a.y); r[2] = f2bf_s(a.z); r[3] = f2bf_s(a.w);
  r[4] = f2bf_s(b.x); r[5] = f2bf_s(b.y); r[6] = f2bf_s(b.z); r[7] = f2bf_s(b.w);
  return r;
}

// init: zero hx/cx, convert all weight matrices f32 -> bf16 into ws
__global__ void qlstm_init_kernel(
    const float* __restrict__ Wq, const float* __restrict__ Wk, const float* __restrict__ Wv,
    const float* __restrict__ Wf, const float* __restrict__ Wi,
    const float* __restrict__ Wg, const float* __restrict__ Wo,
    char* __restrict__ wsb) {
  const int gid = blockIdx.x * blockDim.x + threadIdx.x;
  const int stride = gridDim.x * blockDim.x;
  bf16*  hx = (bf16*)(wsb + WS_HX);
  float* cx = (float*)(wsb + WS_CX);
  for (int i = gid; i < 65536; i += stride) { hx[i] = __float2bfloat16(0.0f); cx[i] = 0.0f; }
  const float* srcs[7] = { Wq, Wk, Wv, Wf, Wi, Wg, Wo };
  const int offs[7] = { WS_WQ, WS_WK, WS_WV, WS_WF, WS_WI, WS_WG, WS_WO };
  const int lens[7] = { 262144, 262144, 262144, 131072, 131072, 131072, 131072 };
  for (int a = 0; a < 7; ++a) {
    bf16* dst = (bf16*)(wsb + offs[a]);
    const float* src = srcs[a];
    for (int i = gid; i < lens[a]; i += stride) dst[i] = __float2bfloat16(src[i]);
  }
}

__global__ void __launch_bounds__(256, 1) qlstm_main_kernel(
    const float* __restrict__ x,
    const float* __restrict__ bfv, const float* __restrict__ biv,
    const float* __restrict__ bgv, const float* __restrict__ bov,
    float* __restrict__ out, char* __restrict__ wsb)
{
  cg::grid_group grid = cg::this_grid();

  bf16*  q_ws  = (bf16*)(wsb + WS_Q);
  bf16*  k_ws  = (bf16*)(wsb + WS_K);
  bf16*  vT_ws = (bf16*)(wsb + WS_VT);
  bf16*  at_ws = (bf16*)(wsb + WS_AT);
  bf16*  hx_ws = (bf16*)(wsb + WS_HX);
  float* cx_ws = (float*)(wsb + WS_CX);
  const bf16* wq_b = (const bf16*)(wsb + WS_WQ);
  const bf16* wk_b = (const bf16*)(wsb + WS_WK);
  const bf16* wv_b = (const bf16*)(wsb + WS_WV);
  const bf16* wf_b = (const bf16*)(wsb + WS_WF);
  const bf16* wi_b = (const bf16*)(wsb + WS_WI);
  const bf16* wg_b = (const bf16*)(wsb + WS_WG);
  const bf16* wo_b = (const bf16*)(wsb + WS_WO);

  const int wg   = blockIdx.x;
  const int tid  = threadIdx.x;
  const int wid  = tid >> 6;     // wave 0..3
  const int lane = tid & 63;
  const int l16  = lane & 15;
  const int kq   = lane >> 4;    // 0..3

  __shared__ float          s_lds[16 * 256];   // scores strip (f32)
  __shared__ unsigned short p_lds[16 * 264];   // softmax probs bf16, +8 pad/row
  __shared__ float          g_lds[4 * 256];    // f,i,g,o 16x16 tiles

  for (int t = 0; t < SEQ; ++t) {
    // ---------------- Phase A: q,k,vT ----------------
    {
      const int gwave = wg * 4 + wid;          // 0..1023
      for (int T = gwave; T < 1536; T += 1024) {
        const int rb = T / 96;
        const int cb = T - rb * 96;
        const bf16* W; int n0;
        if (cb < 32)      { W = wq_b; n0 = cb * 16; }
        else if (cb < 64) { W = wk_b; n0 = (cb - 32) * 16; }
        else              { W = wv_b; n0 = (cb - 64) * 16; }
        const int arow = rb * 16 + l16;
        const float* xrow = x + ((size_t)t * BB + arow) * DD;   // f32
        const bf16*  hrow = hx_ws + arow * HH;                  // bf16
        const bf16*  wrow = W + (size_t)(n0 + l16) * EE;
        f32x4 acc = {0.f, 0.f, 0.f, 0.f};
        #pragma unroll
        for (int ks = 0; ks < 16; ++ks) {
          const int kg = ks * 32 + kq * 8;
          bf16x8 a;
          if (ks < 8) {
            const float4* xf = (const float4*)(xrow + kg);
            a = cvt8(xf[0], xf[1]);
          } else {
            a = *(const bf16x8*)(hrow + (kg - 256));
          }
          bf16x8 b = *(const bf16x8*)(wrow + kg);
          acc = __builtin_amdgcn_mfma_f32_16x16x32_bf16(a, b, acc, 0, 0, 0);
        }
        if (cb < 64) {
          bf16* dst = (cb < 32) ? q_ws : k_ws;
          const int colg = (cb & 31) * 16 + l16;
          #pragma unroll
          for (int r = 0; r < 4; ++r) {
            const int rowg = rb * 16 + kq * 4 + r;
            dst[rowg * EE + colg] = __float2bfloat16(acc[r]);
          }
        } else {
          const int nv = (cb - 64) * 16 + l16;   // v column -> vT row
          const int i0 = rb * 16 + kq * 4;       // batch row base
          #pragma unroll
          for (int r = 0; r < 4; ++r)
            vT_ws[nv * BB + i0 + r] = __float2bfloat16(acc[r]);
        }
      }
    }
    grid.sync();

    // ---------------- Phase BCD: scores/softmax/attn (strip-local) ----------------
    if (wg < 16) {
      const int r0 = wg * 16;
      // B: scores strip 16x256, K=512
      #pragma unroll
      for (int q4 = 0; q4 < 4; ++q4) {
        const int j0 = (wid * 4 + q4) * 16;
        const bf16* qrow = q_ws + (size_t)(r0 + l16) * EE;
        const bf16* krow = k_ws + (size_t)(j0 + l16) * EE;
        f32x4 acc = {0.f, 0.f, 0.f, 0.f};
        #pragma unroll
        for (int ks = 0; ks < 16; ++ks) {
          const int kg = ks * 32 + kq * 8;
          bf16x8 a = *(const bf16x8*)(qrow + kg);
          bf16x8 b = *(const bf16x8*)(krow + kg);
          acc = __builtin_amdgcn_mfma_f32_16x16x32_bf16(a, b, acc, 0, 0, 0);
        }
        #pragma unroll
        for (int r = 0; r < 4; ++r)
          s_lds[(kq * 4 + r) * 256 + j0 + l16] = acc[r];
      }
      __syncthreads();
      // C: softmax rows (scale folded into exp; max-subtracted)
      #pragma unroll
      for (int rr = 0; rr < 4; ++rr) {
        const int i = wid * 4 + rr;
        const float4 v = *(const float4*)(&s_lds[i * 256 + lane * 4]);
        float m = fmaxf(fmaxf(v.x, v.y), fmaxf(v.z, v.w));
        #pragma unroll
        for (int off = 32; off > 0; off >>= 1) m = fmaxf(m, __shfl_xor(m, off));
        float e0 = __expf((v.x - m) * QK_SCALE);
        float e1 = __expf((v.y - m) * QK_SCALE);
        float e2 = __expf((v.z - m) * QK_SCALE);
        float e3 = __expf((v.w - m) * QK_SCALE);
        float s = e0 + e1 + e2 + e3;
        #pragma unroll
        for (int off = 32; off > 0; off >>= 1) s += __shfl_xor(s, off);
        const float rinv = 1.0f / s;
        unsigned short* pp = &p_lds[i * 264 + lane * 4];
        pp[0] = (unsigned short)f2bf_s(e0 * rinv);
        pp[1] = (unsigned short)f2bf_s(e1 * rinv);
        pp[2] = (unsigned short)f2bf_s(e2 * rinv);
        pp[3] = (unsigned short)f2bf_s(e3 * rinv);
      }
      __syncthreads();
      // D: attn strip 16x512, K=256 (B from vT => contiguous)
      #pragma unroll
      for (int q8 = 0; q8 < 8; ++q8) {
        const int n0 = (wid * 8 + q8) * 16;
        const unsigned short* prow = &p_lds[l16 * 264];
        const bf16* vrow = vT_ws + (size_t)(n0 + l16) * BB;
        f32x4 acc = {0.f, 0.f, 0.f, 0.f};
        #pragma unroll
        for (int ks = 0; ks < 8; ++ks) {
          const int kg = ks * 32 + kq * 8;
          bf16x8 a = *(const bf16x8*)(prow + kg);
          bf16x8 b = *(const bf16x8*)(vrow + kg);
          acc = __builtin_amdgcn_mfma_f32_16x16x32_bf16(a, b, acc, 0, 0, 0);
        }
        #pragma unroll
        for (int r = 0; r < 4; ++r)
          at_ws[(size_t)(r0 + kq * 4 + r) * EE + n0 + l16] = __float2bfloat16(acc[r]);
      }
    }
    grid.sync();

    // ---------------- Phase E: gates + LSTM update ----------------
    {
      const int rb = wg >> 4, hcb = wg & 15;
      const bf16* Wsel = (wid == 0) ? wf_b : (wid == 1) ? wi_b : (wid == 2) ? wg_b : wo_b;
      const bf16* arow = at_ws + (size_t)(rb * 16 + l16) * EE;
      const bf16* wrow = Wsel + (size_t)(hcb * 16 + l16) * EE;
      f32x4 acc = {0.f, 0.f, 0.f, 0.f};
      #pragma unroll
      for (int ks = 0; ks < 16; ++ks) {
        const int kg = ks * 32 + kq * 8;
        bf16x8 a = *(const bf16x8*)(arow + kg);
        bf16x8 b = *(const bf16x8*)(wrow + kg);
        acc = __builtin_amdgcn_mfma_f32_16x16x32_bf16(a, b, acc, 0, 0, 0);
      }
      #pragma unroll
      for (int r = 0; r < 4; ++r)
        g_lds[wid * 256 + (kq * 4 + r) * 16 + l16] = acc[r];
      __syncthreads();
      const int i = tid >> 4, j = tid & 15;
      const int row = rb * 16 + i, col = hcb * 16 + j;
      const float F = sigm(g_lds[0 * 256 + i * 16 + j] + bfv[col]);
      const float I = sigm(g_lds[1 * 256 + i * 16 + j] + biv[col]);
      const float G = tanhf(g_lds[2 * 256 + i * 16 + j] + bgv[col]);
      const float O = sigm(g_lds[3 * 256 + i * 16 + j] + bov[col]);
      const float c2 = F * cx_ws[row * 256 + col] + I * G;
      const float h  = O * tanhf(c2);
      cx_ws[row * 256 + col] = c2;
      hx_ws[row * 256 + col] = __float2bfloat16(h);
      out[(size_t)t * 65536 + row * 256 + col] = h;
      if (t == SEQ - 1) {
        out[(size_t)SEQ * 65536 + row * 256 + col] = h;              // final hx
        out[(size_t)SEQ * 65536 + 65536 + row * 256 + col] = c2;     // final cx
      }
      __syncthreads();   // protect g_lds before next step's reuse
    }
    grid.sync();
  }
}

extern "C" void kernel_launch(void* const* d_in, const int* in_sizes, int n_in,
                              void* d_out, int out_size, void* d_ws, size_t ws_size,
                              hipStream_t stream) {
  const float* x   = (const float*)d_in[0];
  const float* Wq  = (const float*)d_in[1];
  const float* Wk  = (const float*)d_in[2];
  const float* Wv  = (const float*)d_in[3];
  const float* Wf  = (const float*)d_in[4];
  const float* bfv = (const float*)d_in[5];
  const float* Wi  = (const float*)d_in[6];
  const float* biv = (const float*)d_in[7];
  const float* Wgg = (const float*)d_in[8];
  const float* bgv = (const float*)d_in[9];
  const float* Wo  = (const float*)d_in[10];
  const float* bov = (const float*)d_in[11];
  float* out = (float*)d_out;
  char* wsb = (char*)d_ws;

  hipLaunchKernelGGL(qlstm_init_kernel, dim3(512), dim3(256), 0, stream,
                     Wq, Wk, Wv, Wf, Wi, Wgg, Wo, wsb);

  void* args[] = { (void*)&x, (void*)&bfv, (void*)&biv, (void*)&bgv, (void*)&bov,
                   (void*)&out, (void*)&wsb };
  hipLaunchCooperativeKernel((void*)qlstm_main_kernel, dim3(NWG), dim3(256),
                             args, 0, stream);
}

// Round 4
// 64043.066 us; speedup vs baseline: 1.1011x; 1.1011x over previous
//
#include <hip/hip_runtime.h>
#include <hip/hip_bf16.h>

// QLSTM (S=512,B=256,D=256,H=256,E=512), f32 in/out, bf16 MFMA internals.
// Persistent cooperative kernel, 256 WGs x 1024 threads, 3 custom grid
// barriers per step (monotonic counter, agent-scope release/acquire):
//   A  : q,k,vT = [x_t|hx] @ [Wq|Wk|Wv]^T              (1536 tiles, 6 waves/WG)
//   BCD: scores -> softmax -> attn, strip wg<16         (16 waves/strip)
//   E  : 4 gate GEMMs + LSTM update                     (4 waves/WG)

typedef __hip_bfloat16 bf16;
typedef __attribute__((ext_vector_type(8))) short bf16x8;   // 8 bf16 = 4 VGPR
typedef __attribute__((ext_vector_type(4))) float f32x4;

#define SEQ 512
#define BB  256
#define DD  256
#define HH  256
#define EE  512
#define NWG 256
#define QK_SCALE 0.04419417382415922f  // 1/sqrt(512)

// ws layout (bytes)
#define WS_Q    0          // bf16 [256][512]
#define WS_K    262144     // bf16 [256][512]
#define WS_VT   524288     // bf16 [512][256]  (v transposed)
#define WS_AT   786432     // bf16 [256][512]  (attn)
#define WS_HX   1048576    // bf16 [256][256]
#define WS_CX   1179648    // f32  [256][256]
#define WS_WQ   1441792    // bf16 [512][512]
#define WS_WK   1966080    // bf16 [512][512]
#define WS_WV   2490368    // bf16 [512][512]
#define WS_WF   3014656    // bf16 [256][512]
#define WS_WI   3276800    // bf16 [256][512]
#define WS_WG   3538944    // bf16 [256][512]
#define WS_WO   3801088    // bf16 [256][512]
#define WS_CNT  4063232    // u32 barrier counter
#define WS_END  4063296

__device__ __forceinline__ float sigm(float x) { return 1.0f / (1.0f + __expf(-x)); }

__device__ __forceinline__ short f2bf_s(float f) {
  bf16 h = __float2bfloat16(f);
  return *reinterpret_cast<short*>(&h);
}

__device__ __forceinline__ bf16x8 cvt8(float4 a, float4 b) {
  bf16x8 r;
  r[0] = f2bf_s(a.x); r[1] = f2bf_s(a.y); r[2] = f2bf_s(a.z); r[3] = f2bf_s(a.w);
  r[4] = f2bf_s(b.x); r[5] = f2bf_s(b.y); r[6] = f2bf_s(b.z); r[7] = f2bf_s(b.w);
  return r;
}

// lightweight grid barrier: monotonic counter, one atomic per WG
__device__ __forceinline__ void gbar(unsigned* cnt, unsigned target) {
  __syncthreads();
  if (threadIdx.x == 0) {
    __hip_atomic_fetch_add(cnt, 1u, __ATOMIC_RELEASE, __HIP_MEMORY_SCOPE_AGENT);
    while (__hip_atomic_load(cnt, __ATOMIC_ACQUIRE, __HIP_MEMORY_SCOPE_AGENT) < target) {
      __builtin_amdgcn_s_sleep(1);
    }
  }
  __syncthreads();
}

// init: zero hx/cx/counter, convert all weight matrices f32 -> bf16 into ws
__global__ void qlstm_init_kernel(
    const float* __restrict__ Wq, const float* __restrict__ Wk, const float* __restrict__ Wv,
    const float* __restrict__ Wf, const float* __restrict__ Wi,
    const float* __restrict__ Wg, const float* __restrict__ Wo,
    char* __restrict__ wsb) {
  const int gid = blockIdx.x * blockDim.x + threadIdx.x;
  const int stride = gridDim.x * blockDim.x;
  bf16*  hx = (bf16*)(wsb + WS_HX);
  float* cx = (float*)(wsb + WS_CX);
  if (gid == 0) *(unsigned*)(wsb + WS_CNT) = 0u;
  for (int i = gid; i < 65536; i += stride) { hx[i] = __float2bfloat16(0.0f); cx[i] = 0.0f; }
  const float* srcs[7] = { Wq, Wk, Wv, Wf, Wi, Wg, Wo };
  const int offs[7] = { WS_WQ, WS_WK, WS_WV, WS_WF, WS_WI, WS_WG, WS_WO };
  const int lens[7] = { 262144, 262144, 262144, 131072, 131072, 131072, 131072 };
  for (int a = 0; a < 7; ++a) {
    bf16* dst = (bf16*)(wsb + offs[a]);
    const float* src = srcs[a];
    for (int i = gid; i < lens[a]; i += stride) dst[i] = __float2bfloat16(src[i]);
  }
}

__global__ void __launch_bounds__(1024, 1) qlstm_main_kernel(
    const float* __restrict__ x,
    const float* __restrict__ bfv, const float* __restrict__ biv,
    const float* __restrict__ bgv, const float* __restrict__ bov,
    float* __restrict__ out, char* __restrict__ wsb)
{
  bf16*  q_ws  = (bf16*)(wsb + WS_Q);
  bf16*  k_ws  = (bf16*)(wsb + WS_K);
  bf16*  vT_ws = (bf16*)(wsb + WS_VT);
  bf16*  at_ws = (bf16*)(wsb + WS_AT);
  bf16*  hx_ws = (bf16*)(wsb + WS_HX);
  float* cx_ws = (float*)(wsb + WS_CX);
  const bf16* wq_b = (const bf16*)(wsb + WS_WQ);
  const bf16* wk_b = (const bf16*)(wsb + WS_WK);
  const bf16* wv_b = (const bf16*)(wsb + WS_WV);
  const bf16* wf_b = (const bf16*)(wsb + WS_WF);
  const bf16* wi_b = (const bf16*)(wsb + WS_WI);
  const bf16* wg_b = (const bf16*)(wsb + WS_WG);
  const bf16* wo_b = (const bf16*)(wsb + WS_WO);
  unsigned* cnt = (unsigned*)(wsb + WS_CNT);

  const int wg   = blockIdx.x;
  const int tid  = threadIdx.x;
  const int wid  = tid >> 6;     // wave 0..15
  const int lane = tid & 63;
  const int l16  = lane & 15;
  const int kq   = lane >> 4;    // 0..3

  __shared__ float          s_lds[16 * 256];   // scores strip (f32)
  __shared__ unsigned short p_lds[16 * 264];   // softmax probs bf16, +8 pad/row
  __shared__ float          g_lds[4 * 256];    // f,i,g,o 16x16 tiles

  unsigned bexp = 0;

  for (int t = 0; t < SEQ; ++t) {
    // ---------------- Phase A: q,k,vT (1536 tiles, waves 0..5 of every WG) ----
    if (wid < 6) {
      const int T = wid * 256 + wg;            // 0..1535
      const int rb = T / 96;
      const int cb = T - rb * 96;
      const bf16* W; int n0;
      if (cb < 32)      { W = wq_b; n0 = cb * 16; }
      else if (cb < 64) { W = wk_b; n0 = (cb - 32) * 16; }
      else              { W = wv_b; n0 = (cb - 64) * 16; }
      const int arow = rb * 16 + l16;
      const float* xrow = x + ((size_t)t * BB + arow) * DD;   // f32
      const bf16*  hrow = hx_ws + arow * HH;                  // bf16
      const bf16*  wrow = W + (size_t)(n0 + l16) * EE;
      f32x4 acc = {0.f, 0.f, 0.f, 0.f};
      #pragma unroll
      for (int ks = 0; ks < 16; ++ks) {
        const int kg = ks * 32 + kq * 8;
        bf16x8 a;
        if (ks < 8) {
          const float4* xf = (const float4*)(xrow + kg);
          a = cvt8(xf[0], xf[1]);
        } else {
          a = *(const bf16x8*)(hrow + (kg - 256));
        }
        bf16x8 b = *(const bf16x8*)(wrow + kg);
        acc = __builtin_amdgcn_mfma_f32_16x16x32_bf16(a, b, acc, 0, 0, 0);
      }
      if (cb < 64) {
        bf16* dst = (cb < 32) ? q_ws : k_ws;
        const int colg = (cb & 31) * 16 + l16;
        #pragma unroll
        for (int r = 0; r < 4; ++r) {
          const int rowg = rb * 16 + kq * 4 + r;
          dst[rowg * EE + colg] = __float2bfloat16(acc[r]);
        }
      } else {
        const int nv = (cb - 64) * 16 + l16;   // v column -> vT row
        const int i0 = rb * 16 + kq * 4;       // batch row base
        #pragma unroll
        for (int r = 0; r < 4; ++r)
          vT_ws[nv * BB + i0 + r] = __float2bfloat16(acc[r]);
      }
    }
    gbar(cnt, (++bexp) * NWG);

    // ---------------- Phase BCD: scores/softmax/attn (strip = wg, 16 waves) ---
    if (wg < 16) {
      const int r0 = wg * 16;
      // B: wave wid computes scores tile (r0.., cols wid*16..), K=512
      {
        const int j0 = wid * 16;
        const bf16* qrow = q_ws + (size_t)(r0 + l16) * EE;
        const bf16* krow = k_ws + (size_t)(j0 + l16) * EE;
        f32x4 acc = {0.f, 0.f, 0.f, 0.f};
        #pragma unroll
        for (int ks = 0; ks < 16; ++ks) {
          const int kg = ks * 32 + kq * 8;
          bf16x8 a = *(const bf16x8*)(qrow + kg);
          bf16x8 b = *(const bf16x8*)(krow + kg);
          acc = __builtin_amdgcn_mfma_f32_16x16x32_bf16(a, b, acc, 0, 0, 0);
        }
        #pragma unroll
        for (int r = 0; r < 4; ++r)
          s_lds[(kq * 4 + r) * 256 + j0 + l16] = acc[r];
      }
      __syncthreads();
      // C: softmax row i = wid (scale folded into exp; max-subtracted)
      {
        const int i = wid;
        const float4 v = *(const float4*)(&s_lds[i * 256 + lane * 4]);
        float m = fmaxf(fmaxf(v.x, v.y), fmaxf(v.z, v.w));
        #pragma unroll
        for (int off = 32; off > 0; off >>= 1) m = fmaxf(m, __shfl_xor(m, off));
        float e0 = __expf((v.x - m) * QK_SCALE);
        float e1 = __expf((v.y - m) * QK_SCALE);
        float e2 = __expf((v.z - m) * QK_SCALE);
        float e3 = __expf((v.w - m) * QK_SCALE);
        float s = e0 + e1 + e2 + e3;
        #pragma unroll
        for (int off = 32; off > 0; off >>= 1) s += __shfl_xor(s, off);
        const float rinv = 1.0f / s;
        unsigned short* pp = &p_lds[i * 264 + lane * 4];
        pp[0] = (unsigned short)f2bf_s(e0 * rinv);
        pp[1] = (unsigned short)f2bf_s(e1 * rinv);
        pp[2] = (unsigned short)f2bf_s(e2 * rinv);
        pp[3] = (unsigned short)f2bf_s(e3 * rinv);
      }
      __syncthreads();
      // D: wave wid computes attn tiles (r0.., n0 = wid*16 + q8*256), K=256
      #pragma unroll
      for (int q8 = 0; q8 < 2; ++q8) {
        const int n0 = wid * 16 + q8 * 256;
        const unsigned short* prow = &p_lds[l16 * 264];
        const bf16* vrow = vT_ws + (size_t)(n0 + l16) * BB;
        f32x4 acc = {0.f, 0.f, 0.f, 0.f};
        #pragma unroll
        for (int ks = 0; ks < 8; ++ks) {
          const int kg = ks * 32 + kq * 8;
          bf16x8 a = *(const bf16x8*)(prow + kg);
          bf16x8 b = *(const bf16x8*)(vrow + kg);
          acc = __builtin_amdgcn_mfma_f32_16x16x32_bf16(a, b, acc, 0, 0, 0);
        }
        #pragma unroll
        for (int r = 0; r < 4; ++r)
          at_ws[(size_t)(r0 + kq * 4 + r) * EE + n0 + l16] = __float2bfloat16(acc[r]);
      }
    }
    gbar(cnt, (++bexp) * NWG);

    // ---------------- Phase E: gates + LSTM update ----------------
    {
      const int rb = wg >> 4, hcb = wg & 15;
      if (wid < 4) {
        const bf16* Wsel = (wid == 0) ? wf_b : (wid == 1) ? wi_b : (wid == 2) ? wg_b : wo_b;
        const bf16* arow = at_ws + (size_t)(rb * 16 + l16) * EE;
        const bf16* wrow = Wsel + (size_t)(hcb * 16 + l16) * EE;
        f32x4 acc = {0.f, 0.f, 0.f, 0.f};
        #pragma unroll
        for (int ks = 0; ks < 16; ++ks) {
          const int kg = ks * 32 + kq * 8;
          bf16x8 a = *(const bf16x8*)(arow + kg);
          bf16x8 b = *(const bf16x8*)(wrow + kg);
          acc = __builtin_amdgcn_mfma_f32_16x16x32_bf16(a, b, acc, 0, 0, 0);
        }
        #pragma unroll
        for (int r = 0; r < 4; ++r)
          g_lds[wid * 256 + (kq * 4 + r) * 16 + l16] = acc[r];
      }
      __syncthreads();
      if (tid < 256) {
        const int i = tid >> 4, j = tid & 15;
        const int row = rb * 16 + i, col = hcb * 16 + j;
        const float F = sigm(g_lds[0 * 256 + i * 16 + j] + bfv[col]);
        const float I = sigm(g_lds[1 * 256 + i * 16 + j] + biv[col]);
        const float G = tanhf(g_lds[2 * 256 + i * 16 + j] + bgv[col]);
        const float O = sigm(g_lds[3 * 256 + i * 16 + j] + bov[col]);
        const float c2 = F * cx_ws[row * 256 + col] + I * G;
        const float h  = O * tanhf(c2);
        cx_ws[row * 256 + col] = c2;
        hx_ws[row * 256 + col] = __float2bfloat16(h);
        out[(size_t)t * 65536 + row * 256 + col] = h;
        if (t == SEQ - 1) {
          out[(size_t)SEQ * 65536 + row * 256 + col] = h;              // final hx
          out[(size_t)SEQ * 65536 + 65536 + row * 256 + col] = c2;     // final cx
        }
      }
    }
    gbar(cnt, (++bexp) * NWG);
  }
}

extern "C" void kernel_launch(void* const* d_in, const int* in_sizes, int n_in,
                              void* d_out, int out_size, void* d_ws, size_t ws_size,
                              hipStream_t stream) {
  const float* x   = (const float*)d_in[0];
  const float* Wq  = (const float*)d_in[1];
  const float* Wk  = (const float*)d_in[2];
  const float* Wv  = (const float*)d_in[3];
  const float* Wf  = (const float*)d_in[4];
  const float* bfv = (const float*)d_in[5];
  const float* Wi  = (const float*)d_in[6];
  const float* biv = (const float*)d_in[7];
  const float* Wgg = (const float*)d_in[8];
  const float* bgv = (const float*)d_in[9];
  const float* Wo  = (const float*)d_in[10];
  const float* bov = (const float*)d_in[11];
  float* out = (float*)d_out;
  char* wsb = (char*)d_ws;

  hipLaunchKernelGGL(qlstm_init_kernel, dim3(512), dim3(256), 0, stream,
                     Wq, Wk, Wv, Wf, Wi, Wgg, Wo, wsb);

  void* args[] = { (void*)&x, (void*)&bfv, (void*)&biv, (void*)&bgv, (void*)&bov,
                   (void*)&out, (void*)&wsb };
  hipLaunchCooperativeKernel((void*)qlstm_main_kernel, dim3(NWG), dim3(1024),
                             args, 0, stream);
}

// Round 5
// 43329.449 us; speedup vs baseline: 1.6274x; 1.4780x over previous
//
#include <hip/hip_runtime.h>
#include <hip/hip_bf16.h>

// QLSTM (S=512,B=256,D=256,H=256,E=512), f32 in/out, bf16 MFMA internals.
// Persistent cooperative kernel, 256 WGs x 1024 threads, TWO lightweight
// grid barriers per step (relaxed atomics + vmcnt flush; sc1 data path, no
// cache-maintenance fences):
//   A    : q,k,vT = [x_t|hx] @ [Wq|Wk|Wv]^T   (all WGs; comb staged in LDS)
//   BCDE : scores->softmax->attn->gates->LSTM  (strip WGs wg<16, LDS-local)
// Cross-WG data (q/k/vT/hx) via relaxed agent-scope 8B atomics (sc1).

typedef __hip_bfloat16 bf16;
typedef __attribute__((ext_vector_type(8))) short bf16x8;   // 8 bf16 = 4 VGPR
typedef __attribute__((ext_vector_type(4))) float f32x4;
typedef unsigned long long u64;

#define SEQ 512
#define BB  256
#define DD  256
#define HH  256
#define EE  512
#define NWG 256
#define QK_SCALE 0.04419417382415922f  // 1/sqrt(512)

// ws layout (bytes)
#define WS_Q    0          // bf16 [256][512]  batch-major
#define WS_K    262144     // bf16 [256][512]  batch-major
#define WS_VT   524288     // bf16 [512][256]  e-major (v transposed)
#define WS_AT   786432     // (unused)
#define WS_HX   1048576    // bf16 [256][256]  batch-major
#define WS_CX   1179648    // f32  lane-private layout, 256KB
#define WS_WQ   1441792    // bf16 [512][512]
#define WS_WK   1966080    // bf16 [512][512]
#define WS_WV   2490368    // bf16 [512][512]
#define WS_WF   3014656    // bf16 [256][512]
#define WS_WI   3276800    // bf16 [256][512]
#define WS_WG   3538944    // bf16 [256][512]
#define WS_WO   3801088    // bf16 [256][512]
#define WS_CNT  4063232    // u32 barrier counter
#define WS_END  4063296

__device__ __forceinline__ float sigm(float x) { return 1.0f / (1.0f + __expf(-x)); }

__device__ __forceinline__ unsigned short f2bf_s(float f) {
  bf16 h = __float2bfloat16(f);
  return *reinterpret_cast<unsigned short*>(&h);
}
__device__ __forceinline__ u64 pack4(float a, float b, float c, float d) {
  union { unsigned short s[4]; u64 u; } x;
  x.s[0] = f2bf_s(a); x.s[1] = f2bf_s(b); x.s[2] = f2bf_s(c); x.s[3] = f2bf_s(d);
  return x.u;
}
// relaxed agent-scope (sc1) 8B coherent load/store — no cache maintenance
__device__ __forceinline__ u64 lda8(const void* p) {
  return __hip_atomic_load((const u64*)p, __ATOMIC_RELAXED, __HIP_MEMORY_SCOPE_AGENT);
}
__device__ __forceinline__ void sta8(void* p, u64 v) {
  __hip_atomic_store((u64*)p, v, __ATOMIC_RELAXED, __HIP_MEMORY_SCOPE_AGENT);
}
__device__ __forceinline__ bf16x8 ld_frag(const bf16* p) {   // 16B = 2 coherent 8B
  union { u64 u[2]; bf16x8 v; } c;
  c.u[0] = lda8(p); c.u[1] = lda8(p + 4);
  return c.v;
}
__device__ __forceinline__ void st8(bf16* p, f32x4 v) {
  sta8(p, pack4(v[0], v[1], v[2], v[3]));
}

// lightweight grid barrier: vmcnt flush + relaxed add + relaxed spin
__device__ __forceinline__ void gbar(unsigned* cnt, unsigned target) {
  asm volatile("s_waitcnt vmcnt(0)" ::: "memory");  // sc1 stores visible at coherence point
  __syncthreads();
  if (threadIdx.x == 0) {
    __hip_atomic_fetch_add(cnt, 1u, __ATOMIC_RELAXED, __HIP_MEMORY_SCOPE_AGENT);
    while (__hip_atomic_load(cnt, __ATOMIC_RELAXED, __HIP_MEMORY_SCOPE_AGENT) < target)
      __builtin_amdgcn_s_sleep(8);
  }
  __syncthreads();
}

// init: zero hx/cx/counter, convert weights f32 -> bf16 into ws
__global__ void qlstm_init_kernel(
    const float* __restrict__ Wq, const float* __restrict__ Wk, const float* __restrict__ Wv,
    const float* __restrict__ Wf, const float* __restrict__ Wi,
    const float* __restrict__ Wg, const float* __restrict__ Wo,
    char* __restrict__ wsb) {
  const int gid = blockIdx.x * blockDim.x + threadIdx.x;
  const int stride = gridDim.x * blockDim.x;
  bf16*  hx = (bf16*)(wsb + WS_HX);
  float* cx = (float*)(wsb + WS_CX);
  if (gid == 0) *(unsigned*)(wsb + WS_CNT) = 0u;
  for (int i = gid; i < 65536; i += stride) { hx[i] = __float2bfloat16(0.0f); cx[i] = 0.0f; }
  const float* srcs[7] = { Wq, Wk, Wv, Wf, Wi, Wg, Wo };
  const int offs[7] = { WS_WQ, WS_WK, WS_WV, WS_WF, WS_WI, WS_WG, WS_WO };
  const int lens[7] = { 262144, 262144, 262144, 131072, 131072, 131072, 131072 };
  for (int a = 0; a < 7; ++a) {
    bf16* dst = (bf16*)(wsb + offs[a]);
    const float* src = srcs[a];
    for (int i = gid; i < lens[a]; i += stride) dst[i] = __float2bfloat16(src[i]);
  }
}

__global__ void __launch_bounds__(1024, 1) qlstm_main_kernel(
    const float* __restrict__ x,
    const float* __restrict__ bfv, const float* __restrict__ biv,
    const float* __restrict__ bgv, const float* __restrict__ bov,
    float* __restrict__ out, char* __restrict__ wsb)
{
  bf16*  q_ws  = (bf16*)(wsb + WS_Q);
  bf16*  k_ws  = (bf16*)(wsb + WS_K);
  bf16*  vT_ws = (bf16*)(wsb + WS_VT);
  bf16*  hx_ws = (bf16*)(wsb + WS_HX);
  float* cx_ws = (float*)(wsb + WS_CX);
  const bf16* wq_b = (const bf16*)(wsb + WS_WQ);
  const bf16* wk_b = (const bf16*)(wsb + WS_WK);
  const bf16* wv_b = (const bf16*)(wsb + WS_WV);
  const bf16* wf_b = (const bf16*)(wsb + WS_WF);
  const bf16* wi_b = (const bf16*)(wsb + WS_WI);
  const bf16* wg_b = (const bf16*)(wsb + WS_WG);
  const bf16* wo_b = (const bf16*)(wsb + WS_WO);
  unsigned* cnt = (unsigned*)(wsb + WS_CNT);

  const int wg   = blockIdx.x;
  const int tid  = threadIdx.x;
  const int wid  = tid >> 6;     // wave 0..15
  const int lane = tid & 63;
  const int l16  = lane & 15;
  const int kq   = lane >> 4;    // 0..3

  __shared__ float          s_lds[16 * 256];    // scores f32 / h repack
  __shared__ unsigned short p_lds[16 * 264];    // softmax probs bf16 (+8 pad/row)
  __shared__ unsigned short cstage[16 * 520];   // A: comb staging; BCDE: at strip

  const int rb = wg >> 4;        // batch row-block this WG owns in phase A

  unsigned bexp = 0;

  for (int t = 0; t < SEQ; ++t) {
    // ============ Phase A: q,k,vT  (all WGs; 6 tiles each) ============
    {
      // stage comb = [x_t | hx] rows rb*16..+16 into cstage[16][520] (bf16)
      const int row = tid >> 6, off = (tid & 63) * 4;
      const float4 xf = *(const float4*)(x + ((size_t)t * BB + rb * 16 + row) * DD + off);
      *(u64*)(&cstage[row * 520 + off]) = pack4(xf.x, xf.y, xf.z, xf.w);
      *(u64*)(&cstage[row * 520 + 256 + off]) = lda8(hx_ws + (rb * 16 + row) * HH + off);
    }
    __syncthreads();
    if (wid < 6) {
      const int cb = (wg & 15) * 6 + wid;       // 0..95
      const unsigned short* crow = &cstage[l16 * 520];
      if (cb < 64) {
        // q,k: SWAPPED operands -> rows = out-col n, cols = batch
        const bf16* W = (cb < 32) ? wq_b : wk_b;
        const int n0 = (cb & 31) * 16;
        const bf16* wrow = W + (size_t)(n0 + l16) * EE;
        f32x4 acc = {0.f, 0.f, 0.f, 0.f};
        #pragma unroll
        for (int ks = 0; ks < 16; ++ks) {
          const int kg = ks * 32 + kq * 8;
          bf16x8 wf = *(const bf16x8*)(wrow + kg);
          bf16x8 cf = *(const bf16x8*)(crow + kg);
          acc = __builtin_amdgcn_mfma_f32_16x16x32_bf16(wf, cf, acc, 0, 0, 0);
        }
        bf16* dst = (cb < 32) ? q_ws : k_ws;
        st8(dst + (size_t)(rb * 16 + l16) * EE + n0 + kq * 4, acc);   // batch-major, row-contig
      } else {
        // v: normal order -> rows = batch, cols = e  => vT row-contig
        const int n0 = (cb - 64) * 16;
        const bf16* wrow = wv_b + (size_t)(n0 + l16) * EE;
        f32x4 acc = {0.f, 0.f, 0.f, 0.f};
        #pragma unroll
        for (int ks = 0; ks < 16; ++ks) {
          const int kg = ks * 32 + kq * 8;
          bf16x8 cf = *(const bf16x8*)(crow + kg);
          bf16x8 wf = *(const bf16x8*)(wrow + kg);
          acc = __builtin_amdgcn_mfma_f32_16x16x32_bf16(cf, wf, acc, 0, 0, 0);
        }
        st8(vT_ws + (size_t)(n0 + l16) * BB + rb * 16 + kq * 4, acc);
      }
    }
    gbar(cnt, (++bexp) * NWG);

    // ============ Phase BCDE: strip WGs (wg<16) do scores..LSTM ============
    if (wg < 16) {
      const int r0 = wg * 16;
      // ---- B: scores tile (strip rows x cols j0..j0+16), K=512
      {
        const int j0 = wid * 16;
        const bf16* qrow = q_ws + (size_t)(r0 + l16) * EE;
        const bf16* krow = k_ws + (size_t)(j0 + l16) * EE;
        f32x4 acc = {0.f, 0.f, 0.f, 0.f};
        #pragma unroll
        for (int ks = 0; ks < 16; ++ks) {
          const int kg = ks * 32 + kq * 8;
          bf16x8 a = ld_frag(qrow + kg);
          bf16x8 b = ld_frag(krow + kg);
          acc = __builtin_amdgcn_mfma_f32_16x16x32_bf16(a, b, acc, 0, 0, 0);
        }
        #pragma unroll
        for (int r = 0; r < 4; ++r)
          s_lds[(kq * 4 + r) * 256 + j0 + l16] = acc[r];
      }
      __syncthreads();
      // ---- C: softmax row i = wid
      {
        const int i = wid;
        const float4 v = *(const float4*)(&s_lds[i * 256 + lane * 4]);
        float m = fmaxf(fmaxf(v.x, v.y), fmaxf(v.z, v.w));
        #pragma unroll
        for (int off = 32; off > 0; off >>= 1) m = fmaxf(m, __shfl_xor(m, off));
        float e0 = __expf((v.x - m) * QK_SCALE);
        float e1 = __expf((v.y - m) * QK_SCALE);
        float e2 = __expf((v.z - m) * QK_SCALE);
        float e3 = __expf((v.w - m) * QK_SCALE);
        float s = e0 + e1 + e2 + e3;
        #pragma unroll
        for (int off = 32; off > 0; off >>= 1) s += __shfl_xor(s, off);
        const float rinv = 1.0f / s;
        unsigned short* pp = &p_lds[i * 264 + lane * 4];
        pp[0] = f2bf_s(e0 * rinv);
        pp[1] = f2bf_s(e1 * rinv);
        pp[2] = f2bf_s(e2 * rinv);
        pp[3] = f2bf_s(e3 * rinv);
      }
      __syncthreads();
      // ---- D: attn strip -> cstage (LDS), SWAPPED (A=vT rows n, B=P rows i)
      #pragma unroll
      for (int q8 = 0; q8 < 2; ++q8) {
        const int n0 = wid * 16 + q8 * 256;
        const bf16* vrow = vT_ws + (size_t)(n0 + l16) * BB;
        const unsigned short* prow = &p_lds[l16 * 264];
        f32x4 acc = {0.f, 0.f, 0.f, 0.f};
        #pragma unroll
        for (int ks = 0; ks < 8; ++ks) {
          const int kg = ks * 32 + kq * 8;
          bf16x8 vf = ld_frag(vrow + kg);
          bf16x8 pf = *(const bf16x8*)(prow + kg);
          acc = __builtin_amdgcn_mfma_f32_16x16x32_bf16(vf, pf, acc, 0, 0, 0);
        }
        // element (n = n0+kq*4+r, batch i = l16) -> at_lds[i][n] row-contig
        *(u64*)(&cstage[l16 * 520 + n0 + kq * 4]) = pack4(acc[0], acc[1], acc[2], acc[3]);
      }
      __syncthreads();
      // ---- E: gates (wave wid owns hcol block wid*16) + LSTM update in regs
      {
        const unsigned short* arow = &cstage[l16 * 520];
        const bf16* wfr = wf_b + (size_t)(wid * 16 + l16) * EE;
        const bf16* wir = wi_b + (size_t)(wid * 16 + l16) * EE;
        const bf16* wgr = wg_b + (size_t)(wid * 16 + l16) * EE;
        const bf16* wor = wo_b + (size_t)(wid * 16 + l16) * EE;
        f32x4 aF = {0.f,0.f,0.f,0.f}, aI = {0.f,0.f,0.f,0.f};
        f32x4 aG = {0.f,0.f,0.f,0.f}, aO = {0.f,0.f,0.f,0.f};
        #pragma unroll
        for (int ks = 0; ks < 16; ++ks) {
          const int kg = ks * 32 + kq * 8;
          bf16x8 af = *(const bf16x8*)(arow + kg);
          aF = __builtin_amdgcn_mfma_f32_16x16x32_bf16(af, *(const bf16x8*)(wfr + kg), aF, 0, 0, 0);
          aI = __builtin_amdgcn_mfma_f32_16x16x32_bf16(af, *(const bf16x8*)(wir + kg), aI, 0, 0, 0);
          aG = __builtin_amdgcn_mfma_f32_16x16x32_bf16(af, *(const bf16x8*)(wgr + kg), aG, 0, 0, 0);
          aO = __builtin_amdgcn_mfma_f32_16x16x32_bf16(af, *(const bf16x8*)(wor + kg), aO, 0, 0, 0);
        }
        const int col = wid * 16 + l16;
        const float bfc = bfv[col], bic = biv[col], bgc = bgv[col], boc = bov[col];
        float* cxp = cx_ws + ((size_t)(wg * 16 + wid) * 64 + lane) * 4;  // lane-private
        const float4 cxv = *(const float4*)cxp;
        const float cxa[4] = { cxv.x, cxv.y, cxv.z, cxv.w };
        float h4[4], c4v[4];
        #pragma unroll
        for (int r = 0; r < 4; ++r) {
          const float F = sigm(aF[r] + bfc);
          const float I = sigm(aI[r] + bic);
          const float G = tanhf(aG[r] + bgc);
          const float O = sigm(aO[r] + boc);
          const float c2 = F * cxa[r] + I * G;
          c4v[r] = c2;
          h4[r]  = O * tanhf(c2);
        }
        *(float4*)cxp = make_float4(c4v[0], c4v[1], c4v[2], c4v[3]);
        // h tile -> s_lds for row-major repack
        #pragma unroll
        for (int r = 0; r < 4; ++r)
          s_lds[wid * 256 + (kq * 4 + r) * 16 + l16] = h4[r];
        if (t == SEQ - 1) {
          #pragma unroll
          for (int r = 0; r < 4; ++r)
            out[(size_t)SEQ * 65536 + 65536 + (size_t)(r0 + kq * 4 + r) * 256 + col] = c4v[r];
        }
      }
      __syncthreads();
      // ---- repack h: coherent hx store + f32 out store (row-contiguous)
      {
        const int row = tid >> 6, c4 = (tid & 63) * 4;
        float hv[4];
        #pragma unroll
        for (int e = 0; e < 4; ++e)
          hv[e] = s_lds[((c4 + e) >> 4) * 256 + row * 16 + ((c4 + e) & 15)];
        sta8(hx_ws + (size_t)(r0 + row) * HH + c4, pack4(hv[0], hv[1], hv[2], hv[3]));
        *(float4*)(out + (size_t)t * 65536 + (size_t)(r0 + row) * 256 + c4) =
            make_float4(hv[0], hv[1], hv[2], hv[3]);
        if (t == SEQ - 1)
          *(float4*)(out + (size_t)SEQ * 65536 + (size_t)(r0 + row) * 256 + c4) =
              make_float4(hv[0], hv[1], hv[2], hv[3]);
      }
    }
    gbar(cnt, (++bexp) * NWG);
  }
}

extern "C" void kernel_launch(void* const* d_in, const int* in_sizes, int n_in,
                              void* d_out, int out_size, void* d_ws, size_t ws_size,
                              hipStream_t stream) {
  const float* x   = (const float*)d_in[0];
  const float* Wq  = (const float*)d_in[1];
  const float* Wk  = (const float*)d_in[2];
  const float* Wv  = (const float*)d_in[3];
  const float* Wf  = (const float*)d_in[4];
  const float* bfv = (const float*)d_in[5];
  const float* Wi  = (const float*)d_in[6];
  const float* biv = (const float*)d_in[7];
  const float* Wgg = (const float*)d_in[8];
  const float* bgv = (const float*)d_in[9];
  const float* Wo  = (const float*)d_in[10];
  const float* bov = (const float*)d_in[11];
  float* out = (float*)d_out;
  char* wsb = (char*)d_ws;

  hipLaunchKernelGGL(qlstm_init_kernel, dim3(512), dim3(256), 0, stream,
                     Wq, Wk, Wv, Wf, Wi, Wgg, Wo, wsb);

  void* args[] = { (void*)&x, (void*)&bfv, (void*)&biv, (void*)&bgv, (void*)&bov,
                   (void*)&out, (void*)&wsb };
  hipLaunchCooperativeKernel((void*)qlstm_main_kernel, dim3(NWG), dim3(1024),
                             args, 0, stream);
}